// Round 3
// baseline (314.247 us; speedup 1.0000x reference)
//
#include <hip/hip_runtime.h>
#include <math.h>

#define EMBED 256
#define HEADS 8
#define LEVELS 4
#define POINTS 4
#define QN 21760          // Q == V == 21760
#define BS 2
#define MTOT (BS * QN)    // 43520 = 340 * 128

typedef __attribute__((ext_vector_type(8))) short bf16x8;
typedef __attribute__((ext_vector_type(4))) float f32x4;
typedef __attribute__((ext_vector_type(2))) float f32x2;

__device__ inline ushort f2bf(float f) {
  union { float f; uint u; } v; v.f = f;
  uint r = (v.u + 0x7FFFu + ((v.u >> 16) & 1u)) >> 16;
  return (ushort)r;
}
__device__ inline float bflo(uint u) { union { uint u; float f; } v; v.u = u << 16; return v.f; }
__device__ inline float bfhi(uint u) { union { uint u; float f; } v; v.u = u & 0xFFFF0000u; return v.f; }
__device__ inline uint pk2(float lo, float hi) { return (uint)f2bf(lo) | ((uint)f2bf(hi) << 16); }

// async global->LDS, 16 B per lane; lptr must be wave-uniform
__device__ inline void g2l(const ushort* g, ushort* l) {
  __builtin_amdgcn_global_load_lds(
      (const __attribute__((address_space(1))) void*)g,
      (__attribute__((address_space(3))) void*)l, 16, 0, 0);
}

// -------- f32 -> bf16 cast, 8 elems/thread --------
__global__ __launch_bounds__(256) void cast_bf16(const float* __restrict__ x,
                                                 ushort* __restrict__ y) {
  int i = blockIdx.x * 256 + threadIdx.x;
  const float4* xp = (const float4*)x;
  float4 a = xp[2 * i], b = xp[2 * i + 1];
  uint4 o;
  o.x = pk2(a.x, a.y); o.y = pk2(a.z, a.w);
  o.z = pk2(b.x, b.y); o.w = pk2(b.z, b.w);
  ((uint4*)y)[i] = o;
}

// -------- weight prep: W (256, N) f32 -> Wt (N, 256) bf16 --------
__global__ __launch_bounds__(256) void prep_w(const float* __restrict__ W,
                                              ushort* __restrict__ Wt, int N) {
  int idx = blockIdx.x * 256 + threadIdx.x;  // over N*256
  int n = idx >> 8, k = idx & 255;
  Wt[idx] = f2bf(W[(size_t)k * N + n]);
}

// fused W_off(256,256) + W_attn(256,128) -> Wt(384,256) bf16, plus fused bias(384)
__global__ __launch_bounds__(256) void prep_wofflog(
    const float* __restrict__ Woff, const float* __restrict__ Wattn,
    const float* __restrict__ boff, const float* __restrict__ battn,
    ushort* __restrict__ Wt, float* __restrict__ biasf) {
  int idx = blockIdx.x * 256 + threadIdx.x;  // over 384*256
  int n = idx >> 8, k = idx & 255;
  float v = (n < 256) ? Woff[(size_t)k * 256 + n] : Wattn[(size_t)k * 128 + (n - 256)];
  Wt[idx] = f2bf(v);
  if (idx < 384) biasf[idx] = (idx < 256) ? boff[idx] : battn[idx - 256];
}

// -------- MFMA bf16 GEMM, m97-style: global_load_lds staging --------
// A (M,256) bf16, Bt (N,256) bf16. MODE 0: f32 flat (M,N). MODE 1: bf16
// head-split (b*8+h, QN, 32), requires N==256.
template<int MODE>
__global__ __launch_bounds__(256) void gemm_bf16(
    const ushort* __restrict__ A, const ushort* __restrict__ Bt,
    const float* __restrict__ bias, void* __restrict__ Cout, int N) {
  __shared__ ushort As[128 * 32];
  __shared__ ushort Bs[128 * 32];
  const int t = threadIdx.x, wave = t >> 6, lane = t & 63;
  const int bm = blockIdx.y * 128, bn = blockIdx.x * 128;
  const int wm = (wave >> 1) * 64, wn = (wave & 1) * 64;
  const int l15 = lane & 15, l4 = lane >> 4;

  // staging: wave w covers rows [32w,32w+32); lane supplies 16 B
  const int srow = lane >> 2, sch = lane & 3;
  const ushort* Ag = A + (size_t)(bm + 32 * wave + srow) * 256 + sch * 8;
  const ushort* Bg = Bt + (size_t)(bn + 32 * wave + srow) * 256 + sch * 8;
  ushort* la = &As[(32 * wave) * 32];
  ushort* lb = &Bs[(32 * wave) * 32];

  f32x4 acc[4][4];
#pragma unroll
  for (int i = 0; i < 4; ++i)
#pragma unroll
    for (int j = 0; j < 4; ++j) acc[i][j] = (f32x4){0.f, 0.f, 0.f, 0.f};

  for (int k0 = 0; k0 < 256; k0 += 32) {
    __syncthreads();
    g2l(Ag + k0, la);
    g2l(Ag + 16 * 256 + k0, la + 16 * 32);
    g2l(Bg + k0, lb);
    g2l(Bg + 16 * 256 + k0, lb + 16 * 32);
    __syncthreads();

    bf16x8 af[4], bfr[4];
#pragma unroll
    for (int mi = 0; mi < 4; ++mi) af[mi] = *(const bf16x8*)&As[(wm + mi * 16 + l15) * 32 + l4 * 8];
#pragma unroll
    for (int ni = 0; ni < 4; ++ni) bfr[ni] = *(const bf16x8*)&Bs[(wn + ni * 16 + l15) * 32 + l4 * 8];
#pragma unroll
    for (int mi = 0; mi < 4; ++mi)
#pragma unroll
      for (int ni = 0; ni < 4; ++ni)
        acc[mi][ni] = __builtin_amdgcn_mfma_f32_16x16x32_bf16(af[mi], bfr[ni], acc[mi][ni], 0, 0, 0);
  }

#pragma unroll
  for (int mi = 0; mi < 4; ++mi) {
#pragma unroll
    for (int ni = 0; ni < 4; ++ni) {
      int col = bn + wn + ni * 16 + l15;
      float bv = bias[col];
#pragma unroll
      for (int r = 0; r < 4; ++r) {
        int row = bm + wm + mi * 16 + l4 * 4 + r;
        float v = acc[mi][ni][r] + bv;
        if (MODE == 0) {
          ((float*)Cout)[(size_t)row * N + col] = v;
        } else {
          int b = (row >= QN) ? 1 : 0;
          int vpos = row - b * QN;
          int h = col >> 5, c = col & 31;
          ((ushort*)Cout)[((size_t)(b * 8 + h) * QN + vpos) * 32 + c] = f2bf(v);
        }
      }
    }
  }
}

// -------- deformable sampling --------
// val bf16 head-split (b*8+h, V, 32); h = blockIdx&7 for XCD/L2 head locality.
// 4 sub-lanes per (b,q,h), 8 channels each. Clamped unconditional loads;
// packed f32x2 accumulate (v_pk_fma_f32).
__global__ __launch_bounds__(256) void msda_sample(
    const ushort* __restrict__ val, const float* __restrict__ offlog,
    const float* __restrict__ ref, ushort* __restrict__ interm) {
  const int lsz[LEVELS]    = {128, 64, 32, 16};
  const int lstart[LEVELS] = {0, 16384, 20480, 21504};

  int h   = blockIdx.x & 7;
  int z   = blockIdx.x >> 3;
  int sub = threadIdx.x & 3;
  int bq  = z * 64 + (threadIdx.x >> 2);    // 680*64 = 43520 exact
  int b   = (bq >= QN) ? 1 : 0;

  // softmax over 16 logits
  const float* lg = offlog + (size_t)bq * 384 + 256 + h * 16;
  float w[16];
  float m = -1e30f;
#pragma unroll
  for (int s = 0; s < 16; ++s) { w[s] = lg[s]; m = fmaxf(m, w[s]); }
  float sum = 0.f;
#pragma unroll
  for (int s = 0; s < 16; ++s) { w[s] = __expf(w[s] - m); sum += w[s]; }
  float inv = 1.f / sum;

  const float* offp = offlog + (size_t)bq * 384 + h * 32;
  const float* refp = ref + (size_t)bq * 8;
  const ushort* vb  = val + ((size_t)(b * 8 + h) * QN) * 32 + sub * 8;

  f32x2 a0 = {0.f, 0.f}, a1 = {0.f, 0.f}, a2 = {0.f, 0.f}, a3 = {0.f, 0.f};

#pragma unroll
  for (int l = 0; l < LEVELS; ++l) {
    const int   W = lsz[l];
    const float fW = (float)W;
    const int   base = lstart[l];
    const float rx = refp[l * 2 + 0], ry = refp[l * 2 + 1];
#pragma unroll
    for (int p = 0; p < POINTS; ++p) {
      float ox = offp[(l * 4 + p) * 2 + 0];
      float oy = offp[(l * 4 + p) * 2 + 1];
      float x = rx * fW + ox - 0.5f;
      float y = ry * fW + oy - 0.5f;
      float x0f = floorf(x), y0f = floorf(y);
      int   x0 = (int)x0f,   y0 = (int)y0f;
      float fx = x - x0f,    fy = y - y0f;
      float a = w[l * 4 + p] * inv;
      // clamp indices, zero weights for OOB (matches reference semantics)
      int x0c = min(max(x0, 0), W - 1);
      int x1c = min(max(x0 + 1, 0), W - 1);
      int y0c = min(max(y0, 0), W - 1);
      int y1c = min(max(y0 + 1, 0), W - 1);
      float wx0 = (x0 >= 0 && x0 < W) ? (1.f - fx) : 0.f;
      float wx1 = (x0 + 1 >= 0 && x0 + 1 < W) ? fx : 0.f;
      float wy0 = (y0 >= 0 && y0 < W) ? (1.f - fy) : 0.f;
      float wy1 = (y0 + 1 >= 0 && y0 + 1 < W) ? fy : 0.f;
      float w00 = wx0 * wy0 * a, w10 = wx1 * wy0 * a;
      float w01 = wx0 * wy1 * a, w11 = wx1 * wy1 * a;

      const uint4* p00 = (const uint4*)(vb + (size_t)(base + y0c * W + x0c) * 32);
      const uint4* p10 = (const uint4*)(vb + (size_t)(base + y0c * W + x1c) * 32);
      const uint4* p01 = (const uint4*)(vb + (size_t)(base + y1c * W + x0c) * 32);
      const uint4* p11 = (const uint4*)(vb + (size_t)(base + y1c * W + x1c) * 32);
      uint4 u00 = *p00;
      uint4 u10 = *p10;
      uint4 u01 = *p01;
      uint4 u11 = *p11;

      {
        f32x2 wv = {w00, w00}; f32x2 v;
        v.x = bflo(u00.x); v.y = bfhi(u00.x); a0 += v * wv;
        v.x = bflo(u00.y); v.y = bfhi(u00.y); a1 += v * wv;
        v.x = bflo(u00.z); v.y = bfhi(u00.z); a2 += v * wv;
        v.x = bflo(u00.w); v.y = bfhi(u00.w); a3 += v * wv;
      }
      {
        f32x2 wv = {w10, w10}; f32x2 v;
        v.x = bflo(u10.x); v.y = bfhi(u10.x); a0 += v * wv;
        v.x = bflo(u10.y); v.y = bfhi(u10.y); a1 += v * wv;
        v.x = bflo(u10.z); v.y = bfhi(u10.z); a2 += v * wv;
        v.x = bflo(u10.w); v.y = bfhi(u10.w); a3 += v * wv;
      }
      {
        f32x2 wv = {w01, w01}; f32x2 v;
        v.x = bflo(u01.x); v.y = bfhi(u01.x); a0 += v * wv;
        v.x = bflo(u01.y); v.y = bfhi(u01.y); a1 += v * wv;
        v.x = bflo(u01.z); v.y = bfhi(u01.z); a2 += v * wv;
        v.x = bflo(u01.w); v.y = bfhi(u01.w); a3 += v * wv;
      }
      {
        f32x2 wv = {w11, w11}; f32x2 v;
        v.x = bflo(u11.x); v.y = bfhi(u11.x); a0 += v * wv;
        v.x = bflo(u11.y); v.y = bfhi(u11.y); a1 += v * wv;
        v.x = bflo(u11.z); v.y = bfhi(u11.z); a2 += v * wv;
        v.x = bflo(u11.w); v.y = bfhi(u11.w); a3 += v * wv;
      }
    }
  }

  uint4 o;
  o.x = pk2(a0.x, a0.y); o.y = pk2(a1.x, a1.y);
  o.z = pk2(a2.x, a2.y); o.w = pk2(a3.x, a3.y);
  *(uint4*)(interm + (size_t)bq * 256 + h * 32 + sub * 8) = o;
}

extern "C" void kernel_launch(void* const* d_in, const int* in_sizes, int n_in,
                              void* d_out, int out_size, void* d_ws, size_t ws_size,
                              hipStream_t stream) {
  const float* query = (const float*)d_in[0];
  const float* value = (const float*)d_in[1];
  const float* ref   = (const float*)d_in[2];
  const float* W_off  = (const float*)d_in[4];
  const float* b_off  = (const float*)d_in[5];
  const float* W_attn = (const float*)d_in[6];
  const float* b_attn = (const float*)d_in[7];
  const float* W_v    = (const float*)d_in[8];
  const float* b_v    = (const float*)d_in[9];
  const float* W_out  = (const float*)d_in[10];
  const float* b_out  = (const float*)d_in[11];
  float* out = (float*)d_out;

  const size_t szBQC = (size_t)MTOT * EMBED;   // 11,141,120 elems

  // ---- workspace layout (byte offsets, all 256-aligned) ----
  char* wsb = (char*)d_ws;
  ushort* ws_wv      = (ushort*)(wsb + 0);          // 131072 B
  ushort* ws_wofflog = (ushort*)(wsb + 131072);     // 196608 B
  ushort* ws_wout    = (ushort*)(wsb + 327680);     // 131072 B
  float*  ws_biasf   = (float*)(wsb + 458752);      // 1536 B (pad to 4096)
  ushort* ws_val     = (ushort*)(wsb + 462848);     // 22282240 B  bf16 head-split
  ushort* ws_q       = (ushort*)(wsb + 22745088);   // 22282240 B  (reused as interm)
  ushort* ws_interm  = ws_q;
  ushort* ws_v       = (ushort*)(wsb + 45027328);   // region F start (bf16 value)
  float*  ws_offlog  = (float*)(wsb + 45027328);    // f32 (M,384) = 66846720 B (overlaps ws_v, used later)
  size_t need = 45027328 + 66846720;                // ~111.9 MB
  if (ws_size < need) return;

  dim3 blk(256);

  // weight prep
  prep_w<<<dim3(256), blk, 0, stream>>>(W_v, ws_wv, 256);
  prep_w<<<dim3(256), blk, 0, stream>>>(W_out, ws_wout, 256);
  prep_wofflog<<<dim3(384), blk, 0, stream>>>(W_off, W_attn, b_off, b_attn, ws_wofflog, ws_biasf);

  // precast query & value to bf16
  cast_bf16<<<dim3(szBQC / 8 / 256), blk, 0, stream>>>(query, ws_q);
  cast_bf16<<<dim3(szBQC / 8 / 256), blk, 0, stream>>>(value, ws_v);

  // val = value @ W_v + b_v  -> bf16 head-split (must run before offlog overwrites ws_v)
  gemm_bf16<1><<<dim3(2, MTOT / 128), blk, 0, stream>>>(ws_v, ws_wv, b_v, ws_val, 256);
  // offlog = query @ [W_off|W_attn] + bias -> f32 (M,384)
  gemm_bf16<0><<<dim3(3, MTOT / 128), blk, 0, stream>>>(ws_q, ws_wofflog, ws_biasf, ws_offlog, 384);
  // sampling -> interm bf16 (overwrites ws_q, which is dead now)
  msda_sample<<<dim3(680 * 8), blk, 0, stream>>>(ws_val, ws_offlog, ref, ws_interm);
  // out = interm @ W_out + b_out -> f32
  gemm_bf16<0><<<dim3(2, MTOT / 128), blk, 0, stream>>>(ws_interm, ws_wout, b_out, out, 256);
}

// Round 4
// 303.710 us; speedup vs baseline: 1.0347x; 1.0347x over previous
//
#include <hip/hip_runtime.h>
#include <math.h>

#define QN 21760
#define MTOT 43520   // = 340 * 128

typedef __attribute__((ext_vector_type(8))) short bf16x8;
typedef __attribute__((ext_vector_type(4))) float f32x4;
typedef __attribute__((ext_vector_type(2))) float f32x2;

__device__ inline ushort f2bf(float f) {
  union { float f; uint u; } v; v.f = f;
  return (ushort)((v.u + 0x7FFFu + ((v.u >> 16) & 1u)) >> 16);
}
__device__ inline float bflo(uint u) { union { uint u; float f; } v; v.u = u << 16; return v.f; }
__device__ inline float bfhi(uint u) { union { uint u; float f; } v; v.u = u & 0xFFFF0000u; return v.f; }
__device__ inline uint pk2(float lo, float hi) { return (uint)f2bf(lo) | ((uint)f2bf(hi) << 16); }

__device__ inline void g2l(const ushort* g, ushort* l) {
  __builtin_amdgcn_global_load_lds(
      (const __attribute__((address_space(1))) void*)g,
      (__attribute__((address_space(3))) void*)l, 16, 0, 0);
}

// ---------------- fused weight prep ----------------
// blocks 0..255: W_v -> wv_t (256,256)^T bf16
// blocks 256..511: W_out -> wout_t
// blocks 512..895: [W_off|W_attn] -> wol_t (384,256) bf16 + fused bias
__global__ __launch_bounds__(256) void prep_weights(
    const float* __restrict__ Wv, const float* __restrict__ Wout,
    const float* __restrict__ Woff, const float* __restrict__ Wattn,
    const float* __restrict__ boff, const float* __restrict__ battn,
    ushort* __restrict__ wv_t, ushort* __restrict__ wout_t,
    ushort* __restrict__ wol_t, float* __restrict__ biasf) {
  int bidx = blockIdx.x, t = threadIdx.x;
  if (bidx < 256) {
    int idx = bidx * 256 + t; int n = idx >> 8, k = idx & 255;
    wv_t[idx] = f2bf(Wv[(size_t)k * 256 + n]);
  } else if (bidx < 512) {
    int idx = (bidx - 256) * 256 + t; int n = idx >> 8, k = idx & 255;
    wout_t[idx] = f2bf(Wout[(size_t)k * 256 + n]);
  } else {
    int idx = (bidx - 512) * 256 + t; int n = idx >> 8, k = idx & 255;
    float v = (n < 256) ? Woff[(size_t)k * 256 + n] : Wattn[(size_t)k * 128 + (n - 256)];
    wol_t[idx] = f2bf(v);
    if (idx < 384) biasf[idx] = (idx < 256) ? boff[idx] : battn[idx - 256];
  }
}

// ---------------- fused input GEMM (val + offlog), double-buffered ----------------
// grid (5, 340): bx<2 -> val = value@Wv + bv, bf16 head-split out
//                bx>=2 -> offlog = query@[Woff|Wattn] + bias, f32 (M,384)
__global__ __launch_bounds__(256) void gemm_in(
    const float* __restrict__ value, const float* __restrict__ query,
    const ushort* __restrict__ Wv, const ushort* __restrict__ Wol,
    const float* __restrict__ bv, const float* __restrict__ bol,
    ushort* __restrict__ val_out, float* __restrict__ offlog) {
  __shared__ ushort As[2][4096];
  __shared__ ushort Bs[2][4096];
  const int t = threadIdx.x, wave = t >> 6, lane = t & 63;
  const int bx = blockIdx.x, bm = blockIdx.y * 128;
  const bool isVal = bx < 2;
  const float* A = isVal ? value : query;
  const ushort* Bt = isVal ? (Wv + (size_t)bx * 128 * 256)
                           : (Wol + (size_t)(bx - 2) * 128 * 256);
  const int wm = (wave >> 1) * 64, wn = (wave & 1) * 64;
  const int l15 = lane & 15, l4 = lane >> 4;

  const int srow = lane >> 2, sch = lane & 3;
  const ushort* Bg = Bt + (size_t)(32 * wave + srow) * 256 + sch * 8;
  ushort* lb[2] = { &Bs[0][(32 * wave) * 32], &Bs[1][(32 * wave) * 32] };

  f32x4 acc[4][4];
#pragma unroll
  for (int i = 0; i < 4; ++i)
#pragma unroll
    for (int j = 0; j < 4; ++j) acc[i][j] = (f32x4){0.f, 0.f, 0.f, 0.f};

  // preload buffer 0
  {
    float4 pa[4];
#pragma unroll
    for (int i = 0; i < 4; ++i) {
      int c = t + i * 256; int row = c >> 3, part = c & 7;
      pa[i] = *(const float4*)&A[(size_t)(bm + row) * 256 + part * 4];
    }
    g2l(Bg, lb[0]); g2l(Bg + 16 * 256, lb[0] + 16 * 32);
#pragma unroll
    for (int i = 0; i < 4; ++i) {
      int c = t + i * 256; int row = c >> 3, part = c & 7;
      ushort4 hv = { f2bf(pa[i].x), f2bf(pa[i].y), f2bf(pa[i].z), f2bf(pa[i].w) };
      *(ushort4*)&As[0][row * 32 + part * 4] = hv;
    }
  }

  for (int k = 0; k < 8; ++k) {
    __syncthreads();
    const int cur = k & 1, nxt = cur ^ 1;
    float4 pa[4];
    if (k < 7) {
      int k1 = (k + 1) * 32;
#pragma unroll
      for (int i = 0; i < 4; ++i) {
        int c = t + i * 256; int row = c >> 3, part = c & 7;
        pa[i] = *(const float4*)&A[(size_t)(bm + row) * 256 + k1 + part * 4];
      }
      g2l(Bg + k1, lb[nxt]); g2l(Bg + 16 * 256 + k1, lb[nxt] + 16 * 32);
    }
    bf16x8 af[4], bfr[4];
#pragma unroll
    for (int mi = 0; mi < 4; ++mi) af[mi] = *(const bf16x8*)&As[cur][(wm + mi * 16 + l15) * 32 + l4 * 8];
#pragma unroll
    for (int ni = 0; ni < 4; ++ni) bfr[ni] = *(const bf16x8*)&Bs[cur][(wn + ni * 16 + l15) * 32 + l4 * 8];
#pragma unroll
    for (int mi = 0; mi < 4; ++mi)
#pragma unroll
      for (int ni = 0; ni < 4; ++ni)
        acc[mi][ni] = __builtin_amdgcn_mfma_f32_16x16x32_bf16(af[mi], bfr[ni], acc[mi][ni], 0, 0, 0);
    if (k < 7) {
#pragma unroll
      for (int i = 0; i < 4; ++i) {
        int c = t + i * 256; int row = c >> 3, part = c & 7;
        ushort4 hv = { f2bf(pa[i].x), f2bf(pa[i].y), f2bf(pa[i].z), f2bf(pa[i].w) };
        *(ushort4*)&As[nxt][row * 32 + part * 4] = hv;
      }
    }
  }

  if (isVal) {
#pragma unroll
    for (int mi = 0; mi < 4; ++mi)
#pragma unroll
      for (int ni = 0; ni < 4; ++ni) {
        int col = bx * 128 + wn + ni * 16 + l15;
        float bb = bv[col];
        int hh = col >> 5, c = col & 31;
#pragma unroll
        for (int r = 0; r < 4; ++r) {
          int row = bm + wm + mi * 16 + l4 * 4 + r;
          int b = (row >= QN) ? 1 : 0;
          int vpos = row - b * QN;
          val_out[((size_t)(b * 8 + hh) * QN + vpos) * 32 + c] = f2bf(acc[mi][ni][r] + bb);
        }
      }
  } else {
#pragma unroll
    for (int mi = 0; mi < 4; ++mi)
#pragma unroll
      for (int ni = 0; ni < 4; ++ni) {
        int col = (bx - 2) * 128 + wn + ni * 16 + l15;
        float bb = bol[col];
#pragma unroll
        for (int r = 0; r < 4; ++r) {
          int row = bm + wm + mi * 16 + l4 * 4 + r;
          offlog[(size_t)row * 384 + col] = acc[mi][ni][r] + bb;
        }
      }
  }
}

// ---------------- output GEMM (A bf16), double-buffered ----------------
__global__ __launch_bounds__(256) void gemm_out(
    const ushort* __restrict__ A, const ushort* __restrict__ Bt,
    const float* __restrict__ bias, float* __restrict__ C) {
  __shared__ ushort As[2][4096];
  __shared__ ushort Bs[2][4096];
  const int t = threadIdx.x, wave = t >> 6, lane = t & 63;
  const int bm = blockIdx.y * 128, bn = blockIdx.x * 128;
  const int wm = (wave >> 1) * 64, wn = (wave & 1) * 64;
  const int l15 = lane & 15, l4 = lane >> 4;

  const int srow = lane >> 2, sch = lane & 3;
  const ushort* Ag = A + (size_t)(bm + 32 * wave + srow) * 256 + sch * 8;
  const ushort* Bg = Bt + (size_t)(bn + 32 * wave + srow) * 256 + sch * 8;
  ushort* la[2] = { &As[0][(32 * wave) * 32], &As[1][(32 * wave) * 32] };
  ushort* lb[2] = { &Bs[0][(32 * wave) * 32], &Bs[1][(32 * wave) * 32] };

  f32x4 acc[4][4];
#pragma unroll
  for (int i = 0; i < 4; ++i)
#pragma unroll
    for (int j = 0; j < 4; ++j) acc[i][j] = (f32x4){0.f, 0.f, 0.f, 0.f};

  g2l(Ag, la[0]); g2l(Ag + 16 * 256, la[0] + 16 * 32);
  g2l(Bg, lb[0]); g2l(Bg + 16 * 256, lb[0] + 16 * 32);

  for (int k = 0; k < 8; ++k) {
    __syncthreads();
    const int cur = k & 1, nxt = cur ^ 1;
    if (k < 7) {
      int k1 = (k + 1) * 32;
      g2l(Ag + k1, la[nxt]); g2l(Ag + 16 * 256 + k1, la[nxt] + 16 * 32);
      g2l(Bg + k1, lb[nxt]); g2l(Bg + 16 * 256 + k1, lb[nxt] + 16 * 32);
    }
    bf16x8 af[4], bfr[4];
#pragma unroll
    for (int mi = 0; mi < 4; ++mi) af[mi] = *(const bf16x8*)&As[cur][(wm + mi * 16 + l15) * 32 + l4 * 8];
#pragma unroll
    for (int ni = 0; ni < 4; ++ni) bfr[ni] = *(const bf16x8*)&Bs[cur][(wn + ni * 16 + l15) * 32 + l4 * 8];
#pragma unroll
    for (int mi = 0; mi < 4; ++mi)
#pragma unroll
      for (int ni = 0; ni < 4; ++ni)
        acc[mi][ni] = __builtin_amdgcn_mfma_f32_16x16x32_bf16(af[mi], bfr[ni], acc[mi][ni], 0, 0, 0);
  }

#pragma unroll
  for (int mi = 0; mi < 4; ++mi)
#pragma unroll
    for (int ni = 0; ni < 4; ++ni) {
      int col = bn + wn + ni * 16 + l15;
      float bb = bias[col];
#pragma unroll
      for (int r = 0; r < 4; ++r) {
        int row = bm + wm + mi * 16 + l4 * 4 + r;
        C[(size_t)row * 256 + col] = acc[mi][ni][r] + bb;
      }
    }
}

// ---------------- deformable sampling ----------------
// 16 channels/thread (2 sub-lanes per (b,q,h)); conditional corner loads;
// h = blockIdx&7 for per-XCD L2 head locality.
__device__ inline void fma8(f32x2* a, uint4 u, float wv) {
  f32x2 ww = { wv, wv }; f32x2 v;
  v.x = bflo(u.x); v.y = bfhi(u.x); a[0] += v * ww;
  v.x = bflo(u.y); v.y = bfhi(u.y); a[1] += v * ww;
  v.x = bflo(u.z); v.y = bfhi(u.z); a[2] += v * ww;
  v.x = bflo(u.w); v.y = bfhi(u.w); a[3] += v * ww;
}

__global__ __launch_bounds__(256) void msda_sample(
    const ushort* __restrict__ val, const float* __restrict__ offlog,
    const float* __restrict__ ref, ushort* __restrict__ interm) {
  const int lsz[4]    = {128, 64, 32, 16};
  const int lstart[4] = {0, 16384, 20480, 21504};

  int h   = blockIdx.x & 7;
  int z   = blockIdx.x >> 3;          // 0..339
  int sub = threadIdx.x & 1;
  int bq  = z * 128 + (threadIdx.x >> 1);
  int b   = (bq >= QN) ? 1 : 0;

  const float* lgp = offlog + (size_t)bq * 384 + 256 + h * 16;
  float w[16];
  {
    float4 a0 = *(const float4*)(lgp);
    float4 a1 = *(const float4*)(lgp + 4);
    float4 a2 = *(const float4*)(lgp + 8);
    float4 a3 = *(const float4*)(lgp + 12);
    w[0]=a0.x; w[1]=a0.y; w[2]=a0.z; w[3]=a0.w;
    w[4]=a1.x; w[5]=a1.y; w[6]=a1.z; w[7]=a1.w;
    w[8]=a2.x; w[9]=a2.y; w[10]=a2.z; w[11]=a2.w;
    w[12]=a3.x; w[13]=a3.y; w[14]=a3.z; w[15]=a3.w;
  }
  float m = -1e30f;
#pragma unroll
  for (int s = 0; s < 16; ++s) m = fmaxf(m, w[s]);
  float sum = 0.f;
#pragma unroll
  for (int s = 0; s < 16; ++s) { w[s] = __expf(w[s] - m); sum += w[s]; }
  float inv = 1.f / sum;

  const float* offp = offlog + (size_t)bq * 384 + h * 32;
  const float* refp = ref + (size_t)bq * 8;
  const ushort* vb  = val + ((size_t)(b * 8 + h) * QN) * 32 + sub * 16;

  f32x2 acc[8];
#pragma unroll
  for (int i = 0; i < 8; ++i) acc[i] = (f32x2){0.f, 0.f};

#pragma unroll
  for (int l = 0; l < 4; ++l) {
    float4 o0 = *(const float4*)(offp + l * 8);
    float4 o1 = *(const float4*)(offp + l * 8 + 4);
    float ox[4] = { o0.x, o0.z, o1.x, o1.z };
    float oy[4] = { o0.y, o0.w, o1.y, o1.w };
    const int   W = lsz[l];
    const float fW = (float)W;
    const int   base = lstart[l];
    const float rx = refp[l * 2 + 0], ry = refp[l * 2 + 1];
#pragma unroll
    for (int p = 0; p < 4; ++p) {
      float x = rx * fW + ox[p] - 0.5f;
      float y = ry * fW + oy[p] - 0.5f;
      float x0f = floorf(x), y0f = floorf(y);
      int   x0 = (int)x0f,   y0 = (int)y0f;
      float fx = x - x0f,    fy = y - y0f;
      float a = w[l * 4 + p] * inv;
      float wx0 = (x0 >= 0 && x0 < W) ? (1.f - fx) : 0.f;
      float wx1 = (x0 + 1 >= 0 && x0 + 1 < W) ? fx : 0.f;
      float wy0 = (y0 >= 0 && y0 < W) ? (1.f - fy) : 0.f;
      float wy1 = (y0 + 1 >= 0 && y0 + 1 < W) ? fy : 0.f;
      float w00 = wx0 * wy0 * a, w10 = wx1 * wy0 * a;
      float w01 = wx0 * wy1 * a, w11 = wx1 * wy1 * a;

      if (w00 != 0.f) {
        const ushort* pp = vb + (size_t)(base + y0 * W + x0) * 32;
        uint4 u0 = *(const uint4*)pp, u1 = *(const uint4*)(pp + 8);
        fma8(acc, u0, w00); fma8(acc + 4, u1, w00);
      }
      if (w10 != 0.f) {
        const ushort* pp = vb + (size_t)(base + y0 * W + x0 + 1) * 32;
        uint4 u0 = *(const uint4*)pp, u1 = *(const uint4*)(pp + 8);
        fma8(acc, u0, w10); fma8(acc + 4, u1, w10);
      }
      if (w01 != 0.f) {
        const ushort* pp = vb + (size_t)(base + (y0 + 1) * W + x0) * 32;
        uint4 u0 = *(const uint4*)pp, u1 = *(const uint4*)(pp + 8);
        fma8(acc, u0, w01); fma8(acc + 4, u1, w01);
      }
      if (w11 != 0.f) {
        const ushort* pp = vb + (size_t)(base + (y0 + 1) * W + x0 + 1) * 32;
        uint4 u0 = *(const uint4*)pp, u1 = *(const uint4*)(pp + 8);
        fma8(acc, u0, w11); fma8(acc + 4, u1, w11);
      }
    }
  }

  uint4 q0, q1;
  q0.x = pk2(acc[0].x, acc[0].y); q0.y = pk2(acc[1].x, acc[1].y);
  q0.z = pk2(acc[2].x, acc[2].y); q0.w = pk2(acc[3].x, acc[3].y);
  q1.x = pk2(acc[4].x, acc[4].y); q1.y = pk2(acc[5].x, acc[5].y);
  q1.z = pk2(acc[6].x, acc[6].y); q1.w = pk2(acc[7].x, acc[7].y);
  ushort* ip = interm + (size_t)bq * 256 + h * 32 + sub * 16;
  *(uint4*)ip = q0;
  *(uint4*)(ip + 8) = q1;
}

extern "C" void kernel_launch(void* const* d_in, const int* in_sizes, int n_in,
                              void* d_out, int out_size, void* d_ws, size_t ws_size,
                              hipStream_t stream) {
  const float* query = (const float*)d_in[0];
  const float* value = (const float*)d_in[1];
  const float* ref   = (const float*)d_in[2];
  const float* W_off  = (const float*)d_in[4];
  const float* b_off  = (const float*)d_in[5];
  const float* W_attn = (const float*)d_in[6];
  const float* b_attn = (const float*)d_in[7];
  const float* W_v    = (const float*)d_in[8];
  const float* b_v    = (const float*)d_in[9];
  const float* W_out  = (const float*)d_in[10];
  const float* b_out  = (const float*)d_in[11];
  float* out = (float*)d_out;

  // ---- workspace (byte offsets, 256-aligned) ----
  char* wsb = (char*)d_ws;
  ushort* ws_wv     = (ushort*)(wsb + 0);          // 131072 B
  ushort* ws_wol    = (ushort*)(wsb + 131072);     // 196608 B
  ushort* ws_wout   = (ushort*)(wsb + 327680);     // 131072 B
  float*  ws_biasf  = (float*)(wsb + 458752);      // 1536 B (padded)
  ushort* ws_val    = (ushort*)(wsb + 462848);     // 22282240 B bf16 head-split
  ushort* ws_interm = (ushort*)(wsb + 22745088);   // 22282240 B bf16 (M,256)
  float*  ws_offlog = (float*)(wsb + 45027328);    // 66846720 B f32 (M,384)
  size_t need = 45027328 + 66846720;
  if (ws_size < need) return;

  dim3 blk(256);
  prep_weights<<<dim3(896), blk, 0, stream>>>(W_v, W_out, W_off, W_attn, b_off, b_attn,
                                              ws_wv, ws_wout, ws_wol, ws_biasf);
  gemm_in<<<dim3(5, 340), blk, 0, stream>>>(value, query, ws_wv, ws_wol, b_v, ws_biasf,
                                            ws_val, ws_offlog);
  msda_sample<<<dim3(2720), blk, 0, stream>>>(ws_val, ws_offlog, ref, ws_interm);
  gemm_out<<<dim3(2, 340), blk, 0, stream>>>(ws_interm, ws_wout, b_out, out);
}

// Round 5
// 303.384 us; speedup vs baseline: 1.0358x; 1.0011x over previous
//
#include <hip/hip_runtime.h>
#include <math.h>

#define QN 21760
#define MTOT 43520   // = 340 * 128
#define SZBQC 11141120  // MTOT*256

typedef __attribute__((ext_vector_type(8))) short bf16x8;
typedef __attribute__((ext_vector_type(4))) float f32x4;
typedef __attribute__((ext_vector_type(2))) float f32x2;

__device__ inline ushort f2bf(float f) {
  union { float f; uint u; } v; v.f = f;
  return (ushort)((v.u + 0x7FFFu + ((v.u >> 16) & 1u)) >> 16);
}
__device__ inline float bflo(uint u) { union { uint u; float f; } v; v.u = u << 16; return v.f; }
__device__ inline float bfhi(uint u) { union { uint u; float f; } v; v.u = u & 0xFFFF0000u; return v.f; }
__device__ inline uint pk2(float lo, float hi) { return (uint)f2bf(lo) | ((uint)f2bf(hi) << 16); }

__device__ inline void g2l(const ushort* g, ushort* l) {
  __builtin_amdgcn_global_load_lds(
      (const __attribute__((address_space(1))) void*)g,
      (__attribute__((address_space(3))) void*)l, 16, 0, 0);
}

// ---------------- weight prep ----------------
__global__ __launch_bounds__(256) void prep_weights(
    const float* __restrict__ Wv, const float* __restrict__ Wout,
    const float* __restrict__ Woff, const float* __restrict__ Wattn,
    const float* __restrict__ boff, const float* __restrict__ battn,
    ushort* __restrict__ wv_t, ushort* __restrict__ wout_t,
    ushort* __restrict__ wol_t, float* __restrict__ biasf) {
  int bidx = blockIdx.x, t = threadIdx.x;
  if (bidx < 256) {
    int idx = bidx * 256 + t; int n = idx >> 8, k = idx & 255;
    wv_t[idx] = f2bf(Wv[(size_t)k * 256 + n]);
  } else if (bidx < 512) {
    int idx = (bidx - 256) * 256 + t; int n = idx >> 8, k = idx & 255;
    wout_t[idx] = f2bf(Wout[(size_t)k * 256 + n]);
  } else {
    int idx = (bidx - 512) * 256 + t; int n = idx >> 8, k = idx & 255;
    float v = (n < 256) ? Woff[(size_t)k * 256 + n] : Wattn[(size_t)k * 128 + (n - 256)];
    wol_t[idx] = f2bf(v);
    if (idx < 384) biasf[idx] = (idx < 256) ? boff[idx] : battn[idx - 256];
  }
}

// ---------------- fused f32->bf16 cast of value+query ----------------
__global__ __launch_bounds__(256) void cast2_bf16(
    const float* __restrict__ q, const float* __restrict__ v,
    ushort* __restrict__ qo, ushort* __restrict__ vo) {
  int i = blockIdx.x * 256 + threadIdx.x;   // 0 .. 2*SZBQC/8
  const float* src; ushort* dst;
  if (i >= SZBQC / 8) { src = q; dst = qo; i -= SZBQC / 8; }
  else { src = v; dst = vo; }
  const float4* xp = (const float4*)src;
  float4 a = xp[2 * i], b = xp[2 * i + 1];
  uint4 o;
  o.x = pk2(a.x, a.y); o.y = pk2(a.z, a.w);
  o.z = pk2(b.x, b.y); o.w = pk2(b.z, b.w);
  ((uint4*)dst)[i] = o;
}

// ---- XOR-swizzled LDS tile helpers ----
// Tile 128 rows x 32 cols (ushort), row = 64 B = 4 chunks of 16 B.
// Physical chunk of (row, logical chunk c) = c ^ ((row>>1)&3).
// g2l staging: lane supplies global chunk ((lane&3) ^ ((lane>>3)&3)) of row (lane>>2).

// ---------------- fused input GEMM (val + offlog), dbuf, all-g2l ----------------
// grid (5, 340): bx<2 -> val = value@Wv + bv, bf16 head-split out
//                bx>=2 -> offlog = query@[Woff|Wattn] + bias, f32 (M,384)
__global__ __launch_bounds__(256) void gemm_in(
    const ushort* __restrict__ vbf, const ushort* __restrict__ qbf,
    const ushort* __restrict__ Wv, const ushort* __restrict__ Wol,
    const float* __restrict__ bv, const float* __restrict__ bol,
    ushort* __restrict__ val_out, float* __restrict__ offlog) {
  __shared__ ushort As[2][4096];
  __shared__ ushort Bs[2][4096];
  const int t = threadIdx.x, wave = t >> 6, lane = t & 63;
  const int bx = blockIdx.x, bm = blockIdx.y * 128;
  const bool isVal = bx < 2;
  const ushort* A  = isVal ? vbf : qbf;
  const ushort* Bt = isVal ? (Wv + (size_t)bx * 128 * 256)
                           : (Wol + (size_t)(bx - 2) * 128 * 256);
  const int wm = (wave >> 1) * 64, wn = (wave & 1) * 64;
  const int l15 = lane & 15, l4 = lane >> 4;
  const int pc = l4 ^ ((l15 >> 1) & 3);       // physical chunk for frag reads

  const int srow = lane >> 2;
  const int sch  = (lane & 3) ^ ((lane >> 3) & 3);   // swizzled source chunk
  const ushort* Ag = A + (size_t)(bm + 32 * wave + srow) * 256 + sch * 8;
  const ushort* Bg = Bt + (size_t)(32 * wave + srow) * 256 + sch * 8;
  ushort* la[2] = { &As[0][(32 * wave) * 32], &As[1][(32 * wave) * 32] };
  ushort* lb[2] = { &Bs[0][(32 * wave) * 32], &Bs[1][(32 * wave) * 32] };

  f32x4 acc[4][4];
#pragma unroll
  for (int i = 0; i < 4; ++i)
#pragma unroll
    for (int j = 0; j < 4; ++j) acc[i][j] = (f32x4){0.f, 0.f, 0.f, 0.f};

  g2l(Ag, la[0]); g2l(Ag + 16 * 256, la[0] + 16 * 32);
  g2l(Bg, lb[0]); g2l(Bg + 16 * 256, lb[0] + 16 * 32);

  for (int k = 0; k < 8; ++k) {
    __syncthreads();
    const int cur = k & 1, nxt = cur ^ 1;
    if (k < 7) {
      int k1 = (k + 1) * 32;
      g2l(Ag + k1, la[nxt]); g2l(Ag + 16 * 256 + k1, la[nxt] + 16 * 32);
      g2l(Bg + k1, lb[nxt]); g2l(Bg + 16 * 256 + k1, lb[nxt] + 16 * 32);
    }
    bf16x8 af[4], bfr[4];
#pragma unroll
    for (int mi = 0; mi < 4; ++mi)
      af[mi] = *(const bf16x8*)&As[cur][(wm + mi * 16 + l15) * 32 + pc * 8];
#pragma unroll
    for (int ni = 0; ni < 4; ++ni)
      bfr[ni] = *(const bf16x8*)&Bs[cur][(wn + ni * 16 + l15) * 32 + pc * 8];
#pragma unroll
    for (int mi = 0; mi < 4; ++mi)
#pragma unroll
      for (int ni = 0; ni < 4; ++ni)
        acc[mi][ni] = __builtin_amdgcn_mfma_f32_16x16x32_bf16(af[mi], bfr[ni], acc[mi][ni], 0, 0, 0);
  }

  if (isVal) {
#pragma unroll
    for (int mi = 0; mi < 4; ++mi)
#pragma unroll
      for (int ni = 0; ni < 4; ++ni) {
        int col = bx * 128 + wn + ni * 16 + l15;
        float bb = bv[col];
        int hh = col >> 5, c = col & 31;
#pragma unroll
        for (int r = 0; r < 4; ++r) {
          int row = bm + wm + mi * 16 + l4 * 4 + r;
          int b = (row >= QN) ? 1 : 0;
          int vpos = row - b * QN;
          val_out[((size_t)(b * 8 + hh) * QN + vpos) * 32 + c] = f2bf(acc[mi][ni][r] + bb);
        }
      }
  } else {
#pragma unroll
    for (int mi = 0; mi < 4; ++mi)
#pragma unroll
      for (int ni = 0; ni < 4; ++ni) {
        int col = (bx - 2) * 128 + wn + ni * 16 + l15;
        float bb = bol[col];
#pragma unroll
        for (int r = 0; r < 4; ++r) {
          int row = bm + wm + mi * 16 + l4 * 4 + r;
          offlog[(size_t)row * 384 + col] = acc[mi][ni][r] + bb;
        }
      }
  }
}

// ---------------- output GEMM (A bf16), dbuf, all-g2l, swizzled ----------------
__global__ __launch_bounds__(256) void gemm_out(
    const ushort* __restrict__ A, const ushort* __restrict__ Bt,
    const float* __restrict__ bias, float* __restrict__ C) {
  __shared__ ushort As[2][4096];
  __shared__ ushort Bs[2][4096];
  const int t = threadIdx.x, wave = t >> 6, lane = t & 63;
  const int bm = blockIdx.y * 128, bn = blockIdx.x * 128;
  const int wm = (wave >> 1) * 64, wn = (wave & 1) * 64;
  const int l15 = lane & 15, l4 = lane >> 4;
  const int pc = l4 ^ ((l15 >> 1) & 3);

  const int srow = lane >> 2;
  const int sch  = (lane & 3) ^ ((lane >> 3) & 3);
  const ushort* Ag = A + (size_t)(bm + 32 * wave + srow) * 256 + sch * 8;
  const ushort* Bg = Bt + (size_t)(bn + 32 * wave + srow) * 256 + sch * 8;
  ushort* la[2] = { &As[0][(32 * wave) * 32], &As[1][(32 * wave) * 32] };
  ushort* lb[2] = { &Bs[0][(32 * wave) * 32], &Bs[1][(32 * wave) * 32] };

  f32x4 acc[4][4];
#pragma unroll
  for (int i = 0; i < 4; ++i)
#pragma unroll
    for (int j = 0; j < 4; ++j) acc[i][j] = (f32x4){0.f, 0.f, 0.f, 0.f};

  g2l(Ag, la[0]); g2l(Ag + 16 * 256, la[0] + 16 * 32);
  g2l(Bg, lb[0]); g2l(Bg + 16 * 256, lb[0] + 16 * 32);

  for (int k = 0; k < 8; ++k) {
    __syncthreads();
    const int cur = k & 1, nxt = cur ^ 1;
    if (k < 7) {
      int k1 = (k + 1) * 32;
      g2l(Ag + k1, la[nxt]); g2l(Ag + 16 * 256 + k1, la[nxt] + 16 * 32);
      g2l(Bg + k1, lb[nxt]); g2l(Bg + 16 * 256 + k1, lb[nxt] + 16 * 32);
    }
    bf16x8 af[4], bfr[4];
#pragma unroll
    for (int mi = 0; mi < 4; ++mi)
      af[mi] = *(const bf16x8*)&As[cur][(wm + mi * 16 + l15) * 32 + pc * 8];
#pragma unroll
    for (int ni = 0; ni < 4; ++ni)
      bfr[ni] = *(const bf16x8*)&Bs[cur][(wn + ni * 16 + l15) * 32 + pc * 8];
#pragma unroll
    for (int mi = 0; mi < 4; ++mi)
#pragma unroll
      for (int ni = 0; ni < 4; ++ni)
        acc[mi][ni] = __builtin_amdgcn_mfma_f32_16x16x32_bf16(af[mi], bfr[ni], acc[mi][ni], 0, 0, 0);
  }

#pragma unroll
  for (int mi = 0; mi < 4; ++mi)
#pragma unroll
    for (int ni = 0; ni < 4; ++ni) {
      int col = bn + wn + ni * 16 + l15;
      float bb = bias[col];
#pragma unroll
      for (int r = 0; r < 4; ++r) {
        int row = bm + wm + mi * 16 + l4 * 4 + r;
        C[(size_t)row * 256 + col] = acc[mi][ni][r] + bb;
      }
    }
}

// ---------------- deformable sampling ----------------
// 4 sub-lanes per (b,q,h), 8 channels each; h = blockIdx&7 for XCD/L2 locality.
__device__ inline void fma8(f32x2* a, uint4 u, float wv) {
  f32x2 ww = { wv, wv }; f32x2 v;
  v.x = bflo(u.x); v.y = bfhi(u.x); a[0] += v * ww;
  v.x = bflo(u.y); v.y = bfhi(u.y); a[1] += v * ww;
  v.x = bflo(u.z); v.y = bfhi(u.z); a[2] += v * ww;
  v.x = bflo(u.w); v.y = bfhi(u.w); a[3] += v * ww;
}

__global__ __launch_bounds__(256) void msda_sample(
    const ushort* __restrict__ val, const float* __restrict__ offlog,
    const float* __restrict__ ref, ushort* __restrict__ interm) {
  const int lsz[4]    = {128, 64, 32, 16};
  const int lstart[4] = {0, 16384, 20480, 21504};

  int h   = blockIdx.x & 7;
  int z   = blockIdx.x >> 3;          // 0..679
  int sub = threadIdx.x & 3;
  int bq  = z * 64 + (threadIdx.x >> 2);   // 680*64 = 43520
  int b   = (bq >= QN) ? 1 : 0;

  const float* lgp = offlog + (size_t)bq * 384 + 256 + h * 16;
  float w[16];
  {
    float4 a0 = *(const float4*)(lgp);
    float4 a1 = *(const float4*)(lgp + 4);
    float4 a2 = *(const float4*)(lgp + 8);
    float4 a3 = *(const float4*)(lgp + 12);
    w[0]=a0.x; w[1]=a0.y; w[2]=a0.z; w[3]=a0.w;
    w[4]=a1.x; w[5]=a1.y; w[6]=a1.z; w[7]=a1.w;
    w[8]=a2.x; w[9]=a2.y; w[10]=a2.z; w[11]=a2.w;
    w[12]=a3.x; w[13]=a3.y; w[14]=a3.z; w[15]=a3.w;
  }
  float m = -1e30f;
#pragma unroll
  for (int s = 0; s < 16; ++s) m = fmaxf(m, w[s]);
  float sum = 0.f;
#pragma unroll
  for (int s = 0; s < 16; ++s) { w[s] = __expf(w[s] - m); sum += w[s]; }
  float inv = 1.f / sum;

  const float* offp = offlog + (size_t)bq * 384 + h * 32;
  const float* refp = ref + (size_t)bq * 8;
  const ushort* vb  = val + ((size_t)(b * 8 + h) * QN) * 32 + sub * 8;

  f32x2 acc[4];
#pragma unroll
  for (int i = 0; i < 4; ++i) acc[i] = (f32x2){0.f, 0.f};

#pragma unroll
  for (int l = 0; l < 4; ++l) {
    float4 o0 = *(const float4*)(offp + l * 8);
    float4 o1 = *(const float4*)(offp + l * 8 + 4);
    float ox[4] = { o0.x, o0.z, o1.x, o1.z };
    float oy[4] = { o0.y, o0.w, o1.y, o1.w };
    const int   W = lsz[l];
    const float fW = (float)W;
    const int   base = lstart[l];
    const float rx = refp[l * 2 + 0], ry = refp[l * 2 + 1];
#pragma unroll
    for (int p = 0; p < 4; ++p) {
      float x = rx * fW + ox[p] - 0.5f;
      float y = ry * fW + oy[p] - 0.5f;
      float x0f = floorf(x), y0f = floorf(y);
      int   x0 = (int)x0f,   y0 = (int)y0f;
      float fx = x - x0f,    fy = y - y0f;
      float a = w[l * 4 + p] * inv;
      const ushort* r0 = vb + (size_t)(base + y0 * W + x0) * 32;
      const ushort* r1 = r0 + (size_t)W * 32;

      if (x0 >= 0 && y0 >= 0 && x0 + 1 < W && y0 + 1 < W) {
        // interior fast path: 4 loads issued back-to-back
        uint4 u00 = *(const uint4*)r0;
        uint4 u10 = *(const uint4*)(r0 + 32);
        uint4 u01 = *(const uint4*)r1;
        uint4 u11 = *(const uint4*)(r1 + 32);
        float w00 = (1.f - fx) * (1.f - fy) * a;
        float w10 = fx * (1.f - fy) * a;
        float w01 = (1.f - fx) * fy * a;
        float w11 = fx * fy * a;
        fma8(acc, u00, w00); fma8(acc, u10, w10);
        fma8(acc, u01, w01); fma8(acc, u11, w11);
      } else {
        float wx0 = (x0 >= 0 && x0 < W) ? (1.f - fx) : 0.f;
        float wx1 = (x0 + 1 >= 0 && x0 + 1 < W) ? fx : 0.f;
        float wy0 = (y0 >= 0 && y0 < W) ? (1.f - fy) : 0.f;
        float wy1 = (y0 + 1 >= 0 && y0 + 1 < W) ? fy : 0.f;
        float w00 = wx0 * wy0 * a, w10 = wx1 * wy0 * a;
        float w01 = wx0 * wy1 * a, w11 = wx1 * wy1 * a;
        if (w00 != 0.f) { uint4 u = *(const uint4*)r0;        fma8(acc, u, w00); }
        if (w10 != 0.f) { uint4 u = *(const uint4*)(r0 + 32); fma8(acc, u, w10); }
        if (w01 != 0.f) { uint4 u = *(const uint4*)r1;        fma8(acc, u, w01); }
        if (w11 != 0.f) { uint4 u = *(const uint4*)(r1 + 32); fma8(acc, u, w11); }
      }
    }
  }

  uint4 o;
  o.x = pk2(acc[0].x, acc[0].y); o.y = pk2(acc[1].x, acc[1].y);
  o.z = pk2(acc[2].x, acc[2].y); o.w = pk2(acc[3].x, acc[3].y);
  *(uint4*)(interm + (size_t)bq * 256 + h * 32 + sub * 8) = o;
}

extern "C" void kernel_launch(void* const* d_in, const int* in_sizes, int n_in,
                              void* d_out, int out_size, void* d_ws, size_t ws_size,
                              hipStream_t stream) {
  const float* query = (const float*)d_in[0];
  const float* value = (const float*)d_in[1];
  const float* ref   = (const float*)d_in[2];
  const float* W_off  = (const float*)d_in[4];
  const float* b_off  = (const float*)d_in[5];
  const float* W_attn = (const float*)d_in[6];
  const float* b_attn = (const float*)d_in[7];
  const float* W_v    = (const float*)d_in[8];
  const float* b_v    = (const float*)d_in[9];
  const float* W_out  = (const float*)d_in[10];
  const float* b_out  = (const float*)d_in[11];
  float* out = (float*)d_out;

  // ---- workspace (byte offsets, 256-aligned) ----
  char* wsb = (char*)d_ws;
  ushort* ws_wv     = (ushort*)(wsb + 0);          // 131072 B
  ushort* ws_wol    = (ushort*)(wsb + 131072);     // 196608 B
  ushort* ws_wout   = (ushort*)(wsb + 327680);     // 131072 B
  float*  ws_biasf  = (float*)(wsb + 458752);      // 1536 B (padded to 4096)
  ushort* ws_val    = (ushort*)(wsb + 462848);     // 22282240 B bf16 head-split
  ushort* ws_v      = (ushort*)(wsb + 22745088);   // 22282240 B bf16 value
  ushort* ws_q      = (ushort*)(wsb + 45027328);   // 22282240 B bf16 query / interm
  ushort* ws_interm = ws_q;                        // aliased (query dead post-gemm_in)
  float*  ws_offlog = (float*)(wsb + 67309568);    // 66846720 B f32 (M,384)
  size_t need = (size_t)67309568 + 66846720;       // ~134 MB
  if (ws_size < need) return;

  dim3 blk(256);
  prep_weights<<<dim3(896), blk, 0, stream>>>(W_v, W_out, W_off, W_attn, b_off, b_attn,
                                              ws_wv, ws_wout, ws_wol, ws_biasf);
  cast2_bf16<<<dim3(2 * SZBQC / 8 / 256), blk, 0, stream>>>(query, value, ws_q, ws_v);
  gemm_in<<<dim3(5, 340), blk, 0, stream>>>(ws_v, ws_q, ws_wv, ws_wol, b_v, ws_biasf,
                                            ws_val, ws_offlog);
  msda_sample<<<dim3(5440), blk, 0, stream>>>(ws_val, ws_offlog, ref, ws_interm);
  gemm_out<<<dim3(2, 340), blk, 0, stream>>>(ws_interm, ws_wout, b_out, out);
}

// Round 6
// 286.572 us; speedup vs baseline: 1.0966x; 1.0587x over previous
//
#include <hip/hip_runtime.h>
#include <math.h>

#define QN 21760
#define MTOT 43520   // = 340 * 128
#define SZBQC 11141120  // MTOT*256

typedef __attribute__((ext_vector_type(8))) short bf16x8;
typedef __attribute__((ext_vector_type(4))) float f32x4;

__device__ inline ushort f2bf(float f) {
  union { float f; uint u; } v; v.f = f;
  return (ushort)((v.u + 0x7FFFu + ((v.u >> 16) & 1u)) >> 16);
}
__device__ inline uint pk2(float lo, float hi) { return (uint)f2bf(lo) | ((uint)f2bf(hi) << 16); }

__device__ inline void g2l(const ushort* g, ushort* l) {
  __builtin_amdgcn_global_load_lds(
      (const __attribute__((address_space(1))) void*)g,
      (__attribute__((address_space(3))) void*)l, 16, 0, 0);
}

// ---------------- weight prep ----------------
__global__ __launch_bounds__(256) void prep_weights(
    const float* __restrict__ Wv, const float* __restrict__ Wout,
    const float* __restrict__ Woff, const float* __restrict__ Wattn,
    const float* __restrict__ boff, const float* __restrict__ battn,
    ushort* __restrict__ wv_t, ushort* __restrict__ wout_t,
    ushort* __restrict__ wol_t, float* __restrict__ biasf) {
  int bidx = blockIdx.x, t = threadIdx.x;
  if (bidx < 256) {
    int idx = bidx * 256 + t; int n = idx >> 8, k = idx & 255;
    wv_t[idx] = f2bf(Wv[(size_t)k * 256 + n]);
  } else if (bidx < 512) {
    int idx = (bidx - 256) * 256 + t; int n = idx >> 8, k = idx & 255;
    wout_t[idx] = f2bf(Wout[(size_t)k * 256 + n]);
  } else {
    int idx = (bidx - 512) * 256 + t; int n = idx >> 8, k = idx & 255;
    float v = (n < 256) ? Woff[(size_t)k * 256 + n] : Wattn[(size_t)k * 128 + (n - 256)];
    wol_t[idx] = f2bf(v);
    if (idx < 384) biasf[idx] = (idx < 256) ? boff[idx] : battn[idx - 256];
  }
}

// ---- XOR-swizzled LDS tile: 128 rows x 32 ushort; 16B chunk c of row r
// lives at physical chunk c ^ ((r>>1)&3). Frag reads are conflict-free. ----

// ---------------- fused input GEMM (val + offlog) ----------------
// grid (340, 5): by = blockIdx.y selects output panel:
//   by<2  -> val = value@Wv + bv  -> fp16 head-split (b*8+h, QN, 32)
//   by>=2 -> offlog = query@[Woff|Wattn] + bias -> f32 (M,384)
// A is f32; cast fused into LDS staging (dbuf). B staged via g2l (dbuf).
__global__ __launch_bounds__(256) void gemm_in(
    const float* __restrict__ value, const float* __restrict__ query,
    const ushort* __restrict__ Wv, const ushort* __restrict__ Wol,
    const float* __restrict__ bv, const float* __restrict__ bol,
    ushort* __restrict__ val_out, float* __restrict__ offlog) {
  __shared__ ushort As[2][4096];
  __shared__ ushort Bs[2][4096];
  const int t = threadIdx.x, wave = t >> 6, lane = t & 63;
  const int bx = blockIdx.y, bm = blockIdx.x * 128;
  const bool isVal = bx < 2;
  const float* A   = isVal ? value : query;
  const ushort* Bt = isVal ? (Wv + (size_t)bx * 128 * 256)
                           : (Wol + (size_t)(bx - 2) * 128 * 256);
  const int wm = (wave >> 1) * 64, wn = (wave & 1) * 64;
  const int l15 = lane & 15, l4 = lane >> 4;
  const int pc = l4 ^ ((l15 >> 1) & 3);              // frag-read physical chunk

  // B staging (g2l): lane supplies swizzled chunk of its row
  const int srow = lane >> 2;
  const int sch  = (lane & 3) ^ ((lane >> 3) & 3);
  const ushort* Bg = Bt + (size_t)(32 * wave + srow) * 256 + sch * 8;
  ushort* lb[2] = { &Bs[0][(32 * wave) * 32], &Bs[1][(32 * wave) * 32] };

  f32x4 acc[4][4];
#pragma unroll
  for (int i = 0; i < 4; ++i)
#pragma unroll
    for (int j = 0; j < 4; ++j) acc[i][j] = (f32x4){0.f, 0.f, 0.f, 0.f};

  // A staging indices (per thread, 4 pieces of 8 B)
  int arow[4], apart[4];
#pragma unroll
  for (int i = 0; i < 4; ++i) {
    int c = t + i * 256; arow[i] = c >> 3; apart[i] = c & 7;
  }

  // preload buffer 0
  {
    float4 pa[4];
#pragma unroll
    for (int i = 0; i < 4; ++i)
      pa[i] = *(const float4*)&A[(size_t)(bm + arow[i]) * 256 + apart[i] * 4];
    g2l(Bg, lb[0]); g2l(Bg + 16 * 256, lb[0] + 16 * 32);
#pragma unroll
    for (int i = 0; i < 4; ++i) {
      int pc16 = (apart[i] >> 1) ^ ((arow[i] >> 1) & 3);
      ushort4 hv = { f2bf(pa[i].x), f2bf(pa[i].y), f2bf(pa[i].z), f2bf(pa[i].w) };
      *(ushort4*)&As[0][arow[i] * 32 + pc16 * 8 + (apart[i] & 1) * 4] = hv;
    }
  }

  for (int k = 0; k < 8; ++k) {
    __syncthreads();
    const int cur = k & 1, nxt = cur ^ 1;
    float4 pa[4];
    if (k < 7) {
      int k1 = (k + 1) * 32;
#pragma unroll
      for (int i = 0; i < 4; ++i)
        pa[i] = *(const float4*)&A[(size_t)(bm + arow[i]) * 256 + k1 + apart[i] * 4];
      g2l(Bg + k1, lb[nxt]); g2l(Bg + 16 * 256 + k1, lb[nxt] + 16 * 32);
    }
    bf16x8 af[4], bfr[4];
#pragma unroll
    for (int mi = 0; mi < 4; ++mi)
      af[mi] = *(const bf16x8*)&As[cur][(wm + mi * 16 + l15) * 32 + pc * 8];
#pragma unroll
    for (int ni = 0; ni < 4; ++ni)
      bfr[ni] = *(const bf16x8*)&Bs[cur][(wn + ni * 16 + l15) * 32 + pc * 8];
#pragma unroll
    for (int mi = 0; mi < 4; ++mi)
#pragma unroll
      for (int ni = 0; ni < 4; ++ni)
        acc[mi][ni] = __builtin_amdgcn_mfma_f32_16x16x32_bf16(af[mi], bfr[ni], acc[mi][ni], 0, 0, 0);
    if (k < 7) {
#pragma unroll
      for (int i = 0; i < 4; ++i) {
        int pc16 = (apart[i] >> 1) ^ ((arow[i] >> 1) & 3);
        ushort4 hv = { f2bf(pa[i].x), f2bf(pa[i].y), f2bf(pa[i].z), f2bf(pa[i].w) };
        *(ushort4*)&As[nxt][arow[i] * 32 + pc16 * 8 + (apart[i] & 1) * 4] = hv;
      }
    }
  }

  if (isVal) {
    _Float16* vo = (_Float16*)val_out;
#pragma unroll
    for (int mi = 0; mi < 4; ++mi)
#pragma unroll
      for (int ni = 0; ni < 4; ++ni) {
        int col = bx * 128 + wn + ni * 16 + l15;
        float bb = bv[col];
        int hh = col >> 5, c = col & 31;
#pragma unroll
        for (int r = 0; r < 4; ++r) {
          int row = bm + wm + mi * 16 + l4 * 4 + r;
          int b = (row >= QN) ? 1 : 0;
          int vpos = row - b * QN;
          vo[((size_t)(b * 8 + hh) * QN + vpos) * 32 + c] = (_Float16)(acc[mi][ni][r] + bb);
        }
      }
  } else {
#pragma unroll
    for (int mi = 0; mi < 4; ++mi)
#pragma unroll
      for (int ni = 0; ni < 4; ++ni) {
        int col = (bx - 2) * 128 + wn + ni * 16 + l15;
        float bb = bol[col];
#pragma unroll
        for (int r = 0; r < 4; ++r) {
          int row = bm + wm + mi * 16 + l4 * 4 + r;
          offlog[(size_t)row * 384 + col] = acc[mi][ni][r] + bb;
        }
      }
  }
}

// ---------------- output GEMM (A bf16), dbuf, all-g2l, swizzled ----------------
__global__ __launch_bounds__(256) void gemm_out(
    const ushort* __restrict__ A, const ushort* __restrict__ Bt,
    const float* __restrict__ bias, float* __restrict__ C) {
  __shared__ ushort As[2][4096];
  __shared__ ushort Bs[2][4096];
  const int t = threadIdx.x, wave = t >> 6, lane = t & 63;
  const int bm = blockIdx.x * 128, bn = blockIdx.y * 128;
  const int wm = (wave >> 1) * 64, wn = (wave & 1) * 64;
  const int l15 = lane & 15, l4 = lane >> 4;
  const int pc = l4 ^ ((l15 >> 1) & 3);

  const int srow = lane >> 2;
  const int sch  = (lane & 3) ^ ((lane >> 3) & 3);
  const ushort* Ag = A + (size_t)(bm + 32 * wave + srow) * 256 + sch * 8;
  const ushort* Bg = Bt + (size_t)(bn + 32 * wave + srow) * 256 + sch * 8;
  ushort* la[2] = { &As[0][(32 * wave) * 32], &As[1][(32 * wave) * 32] };
  ushort* lb[2] = { &Bs[0][(32 * wave) * 32], &Bs[1][(32 * wave) * 32] };

  f32x4 acc[4][4];
#pragma unroll
  for (int i = 0; i < 4; ++i)
#pragma unroll
    for (int j = 0; j < 4; ++j) acc[i][j] = (f32x4){0.f, 0.f, 0.f, 0.f};

  g2l(Ag, la[0]); g2l(Ag + 16 * 256, la[0] + 16 * 32);
  g2l(Bg, lb[0]); g2l(Bg + 16 * 256, lb[0] + 16 * 32);

  for (int k = 0; k < 8; ++k) {
    __syncthreads();
    const int cur = k & 1, nxt = cur ^ 1;
    if (k < 7) {
      int k1 = (k + 1) * 32;
      g2l(Ag + k1, la[nxt]); g2l(Ag + 16 * 256 + k1, la[nxt] + 16 * 32);
      g2l(Bg + k1, lb[nxt]); g2l(Bg + 16 * 256 + k1, lb[nxt] + 16 * 32);
    }
    bf16x8 af[4], bfr[4];
#pragma unroll
    for (int mi = 0; mi < 4; ++mi)
      af[mi] = *(const bf16x8*)&As[cur][(wm + mi * 16 + l15) * 32 + pc * 8];
#pragma unroll
    for (int ni = 0; ni < 4; ++ni)
      bfr[ni] = *(const bf16x8*)&Bs[cur][(wn + ni * 16 + l15) * 32 + pc * 8];
#pragma unroll
    for (int mi = 0; mi < 4; ++mi)
#pragma unroll
      for (int ni = 0; ni < 4; ++ni)
        acc[mi][ni] = __builtin_amdgcn_mfma_f32_16x16x32_bf16(af[mi], bfr[ni], acc[mi][ni], 0, 0, 0);
  }

#pragma unroll
  for (int mi = 0; mi < 4; ++mi)
#pragma unroll
    for (int ni = 0; ni < 4; ++ni) {
      int col = bn + wn + ni * 16 + l15;
      float bb = bias[col];
#pragma unroll
      for (int r = 0; r < 4; ++r) {
        int row = bm + wm + mi * 16 + l4 * 4 + r;
        C[(size_t)row * 256 + col] = acc[mi][ni][r] + bb;
      }
    }
}

// ---------------- deformable sampling ----------------
// val fp16 head-split (b*8+h, V, 32); h = blockIdx&7 for XCD/L2 locality.
// 4 sub-lanes per (b,q,h), 8 channels each. fp16 fma_mix accumulate.
__device__ inline void fmah(float* a, uint4 u, float wv) {
  union { uint4 u; _Float16 h[8]; } c; c.u = u;
#pragma unroll
  for (int i = 0; i < 8; ++i) a[i] = fmaf((float)c.h[i], wv, a[i]);
}

__global__ __launch_bounds__(256) void msda_sample(
    const ushort* __restrict__ val, const float* __restrict__ offlog,
    const float* __restrict__ ref, ushort* __restrict__ interm) {
  const int lsz[4]    = {128, 64, 32, 16};
  const int lstart[4] = {0, 16384, 20480, 21504};

  int h   = blockIdx.x & 7;
  int z   = blockIdx.x >> 3;          // 0..679
  int sub = threadIdx.x & 3;
  int bq  = z * 64 + (threadIdx.x >> 2);   // 680*64 = 43520
  int b   = (bq >= QN) ? 1 : 0;

  const float* lgp = offlog + (size_t)bq * 384 + 256 + h * 16;
  float w[16];
  {
    float4 a0 = *(const float4*)(lgp);
    float4 a1 = *(const float4*)(lgp + 4);
    float4 a2 = *(const float4*)(lgp + 8);
    float4 a3 = *(const float4*)(lgp + 12);
    w[0]=a0.x; w[1]=a0.y; w[2]=a0.z; w[3]=a0.w;
    w[4]=a1.x; w[5]=a1.y; w[6]=a1.z; w[7]=a1.w;
    w[8]=a2.x; w[9]=a2.y; w[10]=a2.z; w[11]=a2.w;
    w[12]=a3.x; w[13]=a3.y; w[14]=a3.z; w[15]=a3.w;
  }
  float m = -1e30f;
#pragma unroll
  for (int s = 0; s < 16; ++s) m = fmaxf(m, w[s]);
  float sum = 0.f;
#pragma unroll
  for (int s = 0; s < 16; ++s) { w[s] = __expf(w[s] - m); sum += w[s]; }
  float inv = 1.f / sum;

  const float* offp = offlog + (size_t)bq * 384 + h * 32;
  const float* refp = ref + (size_t)bq * 8;
  const ushort* vb  = val + ((size_t)(b * 8 + h) * QN) * 32 + sub * 8;

  float acc[8];
#pragma unroll
  for (int i = 0; i < 8; ++i) acc[i] = 0.f;

#pragma unroll
  for (int l = 0; l < 4; ++l) {
    float4 o0 = *(const float4*)(offp + l * 8);
    float4 o1 = *(const float4*)(offp + l * 8 + 4);
    float ox[4] = { o0.x, o0.z, o1.x, o1.z };
    float oy[4] = { o0.y, o0.w, o1.y, o1.w };
    const int   W = lsz[l];
    const float fW = (float)W;
    const int   base = lstart[l];
    const float rx = refp[l * 2 + 0], ry = refp[l * 2 + 1];
#pragma unroll
    for (int p = 0; p < 4; ++p) {
      float x = rx * fW + ox[p] - 0.5f;
      float y = ry * fW + oy[p] - 0.5f;
      float x0f = floorf(x), y0f = floorf(y);
      int   x0 = (int)x0f,   y0 = (int)y0f;
      float fx = x - x0f,    fy = y - y0f;
      float a = w[l * 4 + p] * inv;
      const ushort* r0 = vb + (size_t)(base + y0 * W + x0) * 32;
      const ushort* r1 = r0 + (size_t)W * 32;

      if (x0 >= 0 && y0 >= 0 && x0 + 1 < W && y0 + 1 < W) {
        uint4 u00 = *(const uint4*)r0;
        uint4 u10 = *(const uint4*)(r0 + 32);
        uint4 u01 = *(const uint4*)r1;
        uint4 u11 = *(const uint4*)(r1 + 32);
        float w00 = (1.f - fx) * (1.f - fy) * a;
        float w10 = fx * (1.f - fy) * a;
        float w01 = (1.f - fx) * fy * a;
        float w11 = fx * fy * a;
        fmah(acc, u00, w00); fmah(acc, u10, w10);
        fmah(acc, u01, w01); fmah(acc, u11, w11);
      } else {
        float wx0 = (x0 >= 0 && x0 < W) ? (1.f - fx) : 0.f;
        float wx1 = (x0 + 1 >= 0 && x0 + 1 < W) ? fx : 0.f;
        float wy0 = (y0 >= 0 && y0 < W) ? (1.f - fy) : 0.f;
        float wy1 = (y0 + 1 >= 0 && y0 + 1 < W) ? fy : 0.f;
        float w00 = wx0 * wy0 * a, w10 = wx1 * wy0 * a;
        float w01 = wx0 * wy1 * a, w11 = wx1 * wy1 * a;
        if (w00 != 0.f) { uint4 u = *(const uint4*)r0;        fmah(acc, u, w00); }
        if (w10 != 0.f) { uint4 u = *(const uint4*)(r0 + 32); fmah(acc, u, w10); }
        if (w01 != 0.f) { uint4 u = *(const uint4*)r1;        fmah(acc, u, w01); }
        if (w11 != 0.f) { uint4 u = *(const uint4*)(r1 + 32); fmah(acc, u, w11); }
      }
    }
  }

  uint4 o;
  o.x = pk2(acc[0], acc[1]); o.y = pk2(acc[2], acc[3]);
  o.z = pk2(acc[4], acc[5]); o.w = pk2(acc[6], acc[7]);
  *(uint4*)(interm + (size_t)bq * 256 + h * 32 + sub * 8) = o;
}

extern "C" void kernel_launch(void* const* d_in, const int* in_sizes, int n_in,
                              void* d_out, int out_size, void* d_ws, size_t ws_size,
                              hipStream_t stream) {
  const float* query = (const float*)d_in[0];
  const float* value = (const float*)d_in[1];
  const float* ref   = (const float*)d_in[2];
  const float* W_off  = (const float*)d_in[4];
  const float* b_off  = (const float*)d_in[5];
  const float* W_attn = (const float*)d_in[6];
  const float* b_attn = (const float*)d_in[7];
  const float* W_v    = (const float*)d_in[8];
  const float* b_v    = (const float*)d_in[9];
  const float* W_out  = (const float*)d_in[10];
  const float* b_out  = (const float*)d_in[11];
  float* out = (float*)d_out;

  // ---- workspace (byte offsets, 256-aligned) ----
  char* wsb = (char*)d_ws;
  ushort* ws_wv     = (ushort*)(wsb + 0);          // 131072 B
  ushort* ws_wol    = (ushort*)(wsb + 131072);     // 196608 B
  ushort* ws_wout   = (ushort*)(wsb + 327680);     // 131072 B
  float*  ws_biasf  = (float*)(wsb + 458752);      // 4096 B
  ushort* ws_val    = (ushort*)(wsb + 462848);     // 22282240 B fp16 head-split
  ushort* ws_interm = (ushort*)(wsb + 22745088);   // 22282240 B bf16 (M,256)
  float*  ws_offlog = (float*)(wsb + 45027328);    // 66846720 B f32 (M,384)
  size_t need = (size_t)45027328 + 66846720;       // ~112 MB
  if (ws_size < need) return;

  dim3 blk(256);
  prep_weights<<<dim3(896), blk, 0, stream>>>(W_v, W_out, W_off, W_attn, b_off, b_attn,
                                              ws_wv, ws_wout, ws_wol, ws_biasf);
  gemm_in<<<dim3(340, 5), blk, 0, stream>>>(value, query, ws_wv, ws_wol, b_v, ws_biasf,
                                            ws_val, ws_offlog);
  msda_sample<<<dim3(5440), blk, 0, stream>>>(ws_val, ws_offlog, ref, ws_interm);
  gemm_out<<<dim3(340, 2), blk, 0, stream>>>(ws_interm, ws_wout, b_out, out);
}